// Round 6
// baseline (4767.267 us; speedup 1.0000x reference)
//
#include <hip/hip_runtime.h>
#include <math.h>

typedef long long i64;

#define EPSF 1e-8f

// ---------------- path metadata ----------------
constexpr int NPATH = 15;
constexpr int PI_[NPATH] = {0,0,1,1,1,1,0,1,1,2,2,2,2,2,2};
constexpr int PF_[NPATH] = {0,1,0,1,1,1,2,2,2,2,2,2,0,1,1};
constexpr int PO_[NPATH] = {0,1,1,0,1,2,2,1,2,0,1,2,2,1,2};
constexpr int ISZ[NPATH] = {1,1,3,3,3,3,1,3,3,5,5,5,5,5,5};
constexpr int FSZ[NPATH] = {1,3,1,3,3,3,5,5,5,5,5,5,1,3,3};
constexpr int OSZ[NPATH] = {1,3,3,1,3,5,5,3,5,1,3,5,5,3,5};
constexpr int IBASE[NPATH] = {0,0,1,1,1,1,0,1,1,4,4,4,4,4,4};
constexpr int FBASE[NPATH] = {0,1,0,1,1,1,4,4,4,4,4,4,0,1,1};
constexpr int OBASE[NPATH] = {0,1,1,0,1,4,4,1,4,0,1,4,4,1,4};
constexpr int CGOFF[NPATH+1] = {0,1,10,19,28,55,100,125,170,245,270,345,470,495,540,615};
// per-path accumulator (i,f) block sizes and offsets
constexpr int AOFF[NPATH+1] = {0,1,4,7,16,25,34,39,54,69,94,119,144,149,164,179};
constexpr int CGTOT = 615;
// path-group split (wave-uniform, balanced acc+w2 registers)
constexpr int PSPL[5] = {0,5,9,12,15};

// ---------------- CG init (device-side, mirrors reference _su2_cg/_q) ----------------
__device__ double dfact(int n){ double r=1.0; for(int i=2;i<=n;++i) r*=(double)i; return r; }

__device__ double su2cg(int j1,int m1,int j2,int m2,int j3,int m3){
  if (m1+m2 != m3) return 0.0;
  int vmin = max(max(-j1+j2+m3, -j1+m1), 0);
  int vmax = min(min(j2+j3+m1, j3-j1+j2), j3+m3);
  if (vmax < vmin) return 0.0;
  double c = sqrt((double)(2*j3+1) * dfact(j3+j1-j2)*dfact(j3-j1+j2)*dfact(j1+j2-j3)
                  * dfact(j3+m3)*dfact(j3-m3)
                  / (dfact(j1+j2+j3+1)*dfact(j1-m1)*dfact(j1+m1)*dfact(j2-m2)*dfact(j2+m2)));
  double s = 0.0;
  for (int v=vmin; v<=vmax; ++v){
    double t = dfact(j2+j3+m1-v)*dfact(j1-m1+v)
             / (dfact(v)*dfact(j3-j1+j2-v)*dfact(j3+m3-v)*dfact(j1-j2-m3+v));
    s += ((v+j2+m2)&1) ? -t : t;
  }
  return c*s;
}

__device__ void qmat_lds(int l, double* qr, double* qi){
  for (int e=0;e<25;e++){ qr[e]=0.0; qi[e]=0.0; }
  const double s2 = 0.70710678118654752440;
  for (int m=-l; m<0; ++m){
    qr[(l+m)*5 + (l-m)] = s2;
    qi[(l+m)*5 + (l+m)] = -s2;
  }
  qr[l*5+l] = 1.0;
  for (int m=1; m<=l; ++m){
    double sg = (m&1)? -1.0 : 1.0;
    qr[(l+m)*5 + (l+m)] = sg*s2;
    qi[(l+m)*5 + (l-m)] = sg*s2;
  }
  if (l==1){
    for (int e=0;e<25;e++){ double r=qr[e], m=qi[e]; qr[e]=m; qi[e]=-r; }
  } else if (l==2){
    for (int e=0;e<25;e++){ qr[e]=-qr[e]; qi[e]=-qi[e]; }
  }
}

__global__ void cg_init_kernel(float* __restrict__ cg){
  int p = blockIdx.x;
  int li = PI_[p], lf = PF_[p], lo = PO_[p];
  int isz = 2*li+1, fsz = 2*lf+1, osz = 2*lo+1;
  __shared__ double sC[125];
  __shared__ double qir[25],qii[25],qfr[25],qfi[25],qor[25],qoi[25];
  if (threadIdx.x==0){
    qmat_lds(li,qir,qii); qmat_lds(lf,qfr,qfi); qmat_lds(lo,qor,qoi);
  }
  int tot = isz*fsz*osz;
  for (int e=threadIdx.x; e<tot; e+=blockDim.x){
    int a = e/(fsz*osz); int r = e%(fsz*osz); int b = r/osz; int n = r%osz;
    sC[e] = su2cg(li, a-li, lf, b-lf, lo, n-lo);
  }
  __syncthreads();
  for (int e=threadIdx.x; e<tot; e+=blockDim.x){
    int mo = e/(isz*fsz); int r = e%(isz*fsz); int ji = r/fsz; int lff = r%fsz;
    double acc = 0.0;
    for (int a=0;a<isz;a++) for(int b=0;b<fsz;b++) for(int n=0;n<osz;n++){
      double s = sC[(a*fsz+b)*osz+n];
      if (s==0.0) continue;
      double r1=qir[a*5+ji],  m1=qii[a*5+ji];
      double r2=qfr[b*5+lff], m2=qfi[b*5+lff];
      double r3=qor[n*5+mo],  m3=-qoi[n*5+mo];
      double rr = r1*r2 - m1*m2;
      double mm = r1*m2 + m1*r2;
      acc += (rr*r3 - mm*m3)*s;
    }
    cg[CGOFF[p] + (mo*isz+ji)*fsz + lff] = (float)acc;
  }
}

// ---------------- helpers ----------------
__device__ __forceinline__ float sspf(float x){
  float sp = (x > 20.f) ? x : log1pf(__expf(x));
  return sp - 0.69314718055994531f;
}

// ---------------- layer-1 self-interaction (one-hot input) ----------------
__global__ void siA1_kernel(const int* __restrict__ types, const float* __restrict__ w,
                            const float* __restrict__ b, float* __restrict__ Vp, int N){
  int idx = blockIdx.x*blockDim.x + threadIdx.x;
  if (idx >= N*24) return;
  int n = idx/24, d = idx%24;
  float v = w[d*3 + types[n]] + b[d];
  float* row = Vp + (i64)idx*12;
  row[0] = v;
  #pragma unroll
  for (int m=1;m<12;m++) row[m]=0.f;
}

// =====================================================================
// conv kernel, cif-factored: per k accumulate acc[c][i][f] += r*Y[f]*Vg[c,i]
// in registers (4 wave-aligned path-groups); CG contraction once per atom
// in the epilogue. w2 rows live in registers (fixed (pg,c) mapping).
// =====================================================================

template<int C, int PS, int PE, int P>
__device__ __forceinline__ void loadw2(const float* __restrict__ gw2, const float* __restrict__ gb2,
                                       int c, float* __restrict__ w2r, float* __restrict__ b2r){
  if constexpr (P < PE){
    constexpr int R = P - PS;
    const float* w = &gw2[(P*C+c)*12];
    #pragma unroll
    for (int q=0;q<3;++q)
      *reinterpret_cast<float4*>(&w2r[R*12+4*q]) = *reinterpret_cast<const float4*>(w+4*q);
    b2r[R] = gb2[P*C+c];
    loadw2<C,PS,PE,P+1>(gw2,gb2,c,w2r,b2r);
  }
}

template<int PS, int PE, int P>
__device__ __forceinline__ void ipaths(const float* __restrict__ w2r, const float* __restrict__ b2r,
                                       const float* __restrict__ sha, const float* __restrict__ Yreg,
                                       const float* __restrict__ vg, float* __restrict__ accR){
  if constexpr (P < PE){
    constexpr int R = P - PS;
    const float* h = &sha[P*12];
    float4 h0 = *reinterpret_cast<const float4*>(h);
    float4 h1 = *reinterpret_cast<const float4*>(h+4);
    float4 h2 = *reinterpret_cast<const float4*>(h+8);
    const float* w = &w2r[R*12];
    float rr = b2r[R]
      + w[0]*h0.x + w[1]*h0.y + w[2]*h0.z + w[3]*h0.w
      + w[4]*h1.x + w[5]*h1.y + w[6]*h1.z + w[7]*h1.w
      + w[8]*h2.x + w[9]*h2.y + w[10]*h2.z + w[11]*h2.w;
    constexpr int LO = AOFF[P] - AOFF[PS];
    float ry[5];
    #pragma unroll
    for (int f=0; f<FSZ[P]; ++f) ry[f] = rr * Yreg[FBASE[P]+f];
    #pragma unroll
    for (int i=0; i<ISZ[P]; ++i){
      const float vv = vg[IBASE[P]+i];
      #pragma unroll
      for (int f=0; f<FSZ[P]; ++f) accR[LO + i*FSZ[P] + f] += ry[f]*vv;
    }
    ipaths<PS,PE,P+1>(w2r,b2r,sha,Yreg,vg,accR);
  }
}

template<int PS, int PE, int P>
__device__ __forceinline__ void epaths(const float* __restrict__ accR, const float* __restrict__ sCG,
                                       float* __restrict__ o){
  if constexpr (P < PE){
    constexpr int LO = AOFF[P] - AOFF[PS];
    #pragma unroll
    for (int om=0; om<OSZ[P]; ++om){
      float s = 0.f;
      #pragma unroll
      for (int i=0; i<ISZ[P]; ++i){
        #pragma unroll
        for (int f=0; f<FSZ[P]; ++f)
          s += sCG[CGOFF[P] + (om*ISZ[P]+i)*FSZ[P] + f] * accR[LO + i*FSZ[P] + f];
      }
      o[OBASE[P]+om] += s;
    }
    epaths<PS,PE,P+1>(accR,sCG,o);
  }
}

template<int C, int A, int T, int HCH>
__global__ __launch_bounds__(T) void conv_kernel(
    const float* __restrict__ Vp, const int* __restrict__ nei_idx, const float* __restrict__ nei_vec,
    const float* __restrict__ gw1, const float* __restrict__ gb1,
    const float* __restrict__ gw2, const float* __restrict__ gb2,
    const float* __restrict__ cg, float* __restrict__ O, int N)
{
  constexpr int GRP = A*C;                // threads per path-group
  static_assert(4*GRP == T, "bad geometry");
  static_assert(GRP % 64 == 0, "pg not wave-aligned");
  constexpr int ACH = A/HCH;              // h-row replication
  constexpr int HTH = 180*ACH;            // h-phase threads
  static_assert(HTH <= T, "h-phase overflow");

  __shared__ float sw1[2160];
  __shared__ float sb1[180];
  __shared__ float sCG[CGTOT];
  __shared__ float srbf[2][A*12];
  __shared__ float sY[2][A*12];
  __shared__ float sh[A*184];
  __shared__ float sRed[3*GRP*9];

  const int t = threadIdx.x;
  const i64 atom0 = (i64)blockIdx.x * A;
  const int pg  = t / GRP;                // wave-uniform
  const int rem = t - pg*GRP;
  const int a = rem / C;
  const int c = rem % C;

  for (int e=t; e<2160;  e+=T) sw1[e]=gw1[e];
  for (int e=t; e<180;   e+=T) sb1[e]=gb1[e];
  for (int e=t; e<CGTOT; e+=T) sCG[e]=cg[e];

  // w2 rows for my path-group -> registers (static indexing only)
  float w2r[5*12];
  float b2r[5];
  if      (pg==0) loadw2<C, 0, 5, 0>(gw2,gb2,c,w2r,b2r);
  else if (pg==1) loadw2<C, 5, 9, 5>(gw2,gb2,c,w2r,b2r);
  else if (pg==2) loadw2<C, 9,12, 9>(gw2,gb2,c,w2r,b2r);
  else            loadw2<C,12,15,12>(gw2,gb2,c,w2r,b2r);

  float accR[75];
  #pragma unroll
  for (int e=0;e<75;++e) accR[e]=0.f;

  auto stage = [&](int kn){
    const int buf = kn & 1;
    if (t < A*12){
      int aa = t/12, j = t - aa*12;
      i64 at = atom0 + aa; if (at >= (i64)N) at = N-1;
      const float* vv = &nei_vec[(at*32 + kn)*3];
      float x=vv[0], y=vv[1], z=vv[2];
      float d = sqrtf(fmaxf(x*x+y*y+z*z, EPSF));
      float dd = d - 0.72727272727272727f*(float)j;
      srbf[buf][t] = __expf(-dd*dd);
    }
    if (t < A){
      i64 at = atom0 + t; if (at >= (i64)N) at = N-1;
      const float* vv = &nei_vec[(at*32 + kn)*3];
      float x=vv[0], y=vv[1], z=vv[2];
      float r2 = fmaxf(x*x+y*y+z*z, EPSF);
      float inv = 1.f/r2;
      float* Ye = &sY[buf][t*12];
      Ye[0]=1.f; Ye[1]=x; Ye[2]=y; Ye[3]=z;
      Ye[4]=x*y*inv; Ye[5]=y*z*inv;
      Ye[6]=(2.f*z*z - x*x - y*y)*(0.28867513459481287f*inv);
      Ye[7]=z*x*inv; Ye[8]=(x*x - y*y)*(0.5f*inv);
      Ye[9]=0.f; Ye[10]=0.f; Ye[11]=0.f;
    }
  };

  stage(0);
  __syncthreads();

  for (int k=0; k<32; ++k){
    const int buf = k & 1;
    // ---- phase 1: h = relu(W1.rbf+b1) for all A rows; stage k+1 ----
    if (t < HTH){
      const int row = t / ACH;            // 0..179 (p*12+hd)
      const int ch  = t - row*ACH;
      const float* w = &sw1[row*12];
      float4 w0 = *reinterpret_cast<const float4*>(w);
      float4 w1 = *reinterpret_cast<const float4*>(w+4);
      float4 w2v= *reinterpret_cast<const float4*>(w+8);
      const float bb = sb1[row];
      #pragma unroll
      for (int q=0; q<HCH; ++q){
        const int aa = ch*HCH + q;
        const float* rb = &srbf[buf][aa*12];
        float4 r0 = *reinterpret_cast<const float4*>(rb);
        float4 r1 = *reinterpret_cast<const float4*>(rb+4);
        float4 r2 = *reinterpret_cast<const float4*>(rb+8);
        float v = bb
          + w0.x*r0.x + w0.y*r0.y + w0.z*r0.z + w0.w*r0.w
          + w1.x*r1.x + w1.y*r1.y + w1.z*r1.z + w1.w*r1.w
          + w2v.x*r2.x + w2v.y*r2.y + w2v.z*r2.z + w2v.w*r2.w;
        sh[aa*184 + row] = fmaxf(v, 0.f);
      }
    }
    if (k+1 < 32) stage(k+1);
    __syncthreads();
    // ---- phase 2: per-(pg,a,c) accumulate outer products ----
    {
      i64 at = atom0 + a; if (at >= (i64)N) at = N-1;
      const int nei = nei_idx[at*32 + k];
      const float* vr = &Vp[((i64)nei*C + c)*12];
      float vg[9];
      float4 v0 = *reinterpret_cast<const float4*>(vr);
      float4 v1 = *reinterpret_cast<const float4*>(vr+4);
      vg[0]=v0.x; vg[1]=v0.y; vg[2]=v0.z; vg[3]=v0.w;
      vg[4]=v1.x; vg[5]=v1.y; vg[6]=v1.z; vg[7]=v1.w;
      vg[8]=vr[8];
      float Yreg[12];
      #pragma unroll
      for (int q=0;q<3;++q)
        *reinterpret_cast<float4*>(&Yreg[4*q]) = *reinterpret_cast<const float4*>(&sY[buf][a*12+4*q]);
      const float* sha = &sh[a*184];
      if      (pg==0) ipaths< 0, 5, 0>(w2r,b2r,sha,Yreg,vg,accR);
      else if (pg==1) ipaths< 5, 9, 5>(w2r,b2r,sha,Yreg,vg,accR);
      else if (pg==2) ipaths< 9,12, 9>(w2r,b2r,sha,Yreg,vg,accR);
      else            ipaths<12,15,12>(w2r,b2r,sha,Yreg,vg,accR);
    }
    __syncthreads();
  }

  // ---- epilogue: CG contraction (once per atom) + cross-pg reduce ----
  float o[9];
  #pragma unroll
  for (int m=0;m<9;++m) o[m]=0.f;
  if      (pg==0) epaths< 0, 5, 0>(accR,sCG,o);
  else if (pg==1) epaths< 5, 9, 5>(accR,sCG,o);
  else if (pg==2) epaths< 9,12, 9>(accR,sCG,o);
  else            epaths<12,15,12>(accR,sCG,o);

  if (pg > 0){
    float* red = &sRed[((pg-1)*GRP + rem)*9];
    #pragma unroll
    for (int m=0;m<9;++m) red[m]=o[m];
  }
  __syncthreads();
  i64 at = atom0 + a;
  if (pg==0 && at < (i64)N){
    #pragma unroll
    for (int g=0; g<3; ++g){
      const float* red = &sRed[(g*GRP + rem)*9];
      #pragma unroll
      for (int m=0;m<9;++m) o[m] += red[m];
    }
    float* orow = O + (at*C + c)*12;
    *reinterpret_cast<float4*>(orow)   = make_float4(o[0],o[1],o[2],o[3]);
    *reinterpret_cast<float4*>(orow+4) = make_float4(o[4],o[5],o[6],o[7]);
    orow[8] = o[8];
  }
}

// ---------------- per-atom norm + siB + per-channel global sums ----------------
template<int C>
__global__ __launch_bounds__(64) void normsiB_kernel(
    const float* __restrict__ O, const float* __restrict__ w, const float* __restrict__ b,
    float* __restrict__ Vb, float* __restrict__ gsum, int N)
{
  __shared__ float sW[C*C];
  __shared__ float sO[C*9];
  __shared__ float sg[2*C];
  const int t = threadIdx.x;
  for (int e=t; e<C*C; e+=64) sW[e]=w[e];
  for (int e=t; e<2*C; e+=64) sg[e]=0.f;
  __syncthreads();
  const int iters = (N + gridDim.x - 1)/gridDim.x;
  for (int it=0; it<iters; ++it){
    i64 at = (i64)blockIdx.x + (i64)it*gridDim.x;
    float p0=0.f,p1=0.f,p2=0.f;
    if (at<(i64)N){
      for (int e=t; e<C*9; e+=64){
        int cc=e/9, m=e-cc*9;
        float v = O[((i64)at*C+cc)*12+m];
        sO[e]=v;
        float vv=v*v;
        if (m==0) p0+=vv; else if (m<4) p1+=vv; else p2+=vv;
      }
    }
    #pragma unroll
    for (int off=1; off<64; off<<=1){
      p0 += __shfl_xor(p0, off);
      p1 += __shfl_xor(p1, off);
      p2 += __shfl_xor(p2, off);
    }
    float i0 = 1.f/sqrtf(fmaxf(p0, EPSF));
    float i1 = 1.f/sqrtf(fmaxf(p1, EPSF));
    float i2 = 1.f/sqrtf(fmaxf(p2, EPSF));
    __syncthreads();
    if (at<(i64)N){
      for (int e=t; e<C*9; e+=64){
        int d=e/9, m=e-d*9;
        float inv = (m==0)? i0 : (m<4)? i1 : i2;
        const float* wr = &sW[d*C];
        float s=0.f;
        #pragma unroll
        for (int cc=0; cc<C; ++cc) s += wr[cc]*sO[cc*9+m];
        float outv = s*inv + ((m==0)? b[d] : 0.f);
        Vb[((i64)at*C+d)*12+m]=outv;
        if (m>=1) atomicAdd(&sg[(m<4?0:1)*C + d], outv*outv);
      }
    }
    __syncthreads();
  }
  for (int e=t; e<2*C; e+=64) atomicAdd(&gsum[e], sg[e]);
}

// ---------------- fused nonlinearity + next-layer siA ----------------
template<int Ci, int Co>
__global__ __launch_bounds__(64) void siaNL_kernel(
    const float* __restrict__ Vb, const float* __restrict__ gsum, const float* __restrict__ nlb,
    const float* __restrict__ w, const float* __restrict__ b, float* __restrict__ Vp, int N)
{
  __shared__ float sW[Co*Ci];
  __shared__ float sIn[Ci*9];
  __shared__ float sT[2*Ci];
  const int t=threadIdx.x;
  for (int e=t; e<Co*Ci; e+=64) sW[e]=w[e];
  for (int e=t; e<2*Ci;  e+=64) sT[e] = sqrtf(gsum[e]) + nlb[e];
  __syncthreads();
  const int iters = (N + gridDim.x - 1)/gridDim.x;
  for (int it=0; it<iters; ++it){
    i64 at = (i64)blockIdx.x + (i64)it*gridDim.x;
    if (at<(i64)N){
      for (int e=t; e<Ci*9; e+=64){
        int cc=e/9, m=e-cc*9;
        float v = Vb[((i64)at*Ci+cc)*12+m];
        float x = (m==0)? sspf(v) : (m<4)? v*sT[cc] : v*sT[Ci+cc];
        sIn[e]=x;
      }
    }
    __syncthreads();
    if (at<(i64)N){
      for (int e=t; e<Co*9; e+=64){
        int d=e/9, m=e-d*9;
        const float* wr=&sW[d*Ci];
        float s = (m==0)? b[d] : 0.f;
        #pragma unroll
        for (int cc=0;cc<Ci;++cc) s += wr[cc]*sIn[cc*9+m];
        Vp[((i64)at*Co+d)*12+m]=s;
      }
    }
    __syncthreads();
  }
}

// ---------------- final readout ----------------
__global__ void final_reduce_kernel(const float* __restrict__ Vb, float* __restrict__ Eacc, int N){
  __shared__ float sE[4];
  const int t=threadIdx.x;
  if (t<4) sE[t]=0.f;
  __syncthreads();
  float a0=0.f,a1=0.f,a2=0.f,a3=0.f;
  for (i64 at = (i64)blockIdx.x*blockDim.x + t; at < (i64)N; at += (i64)gridDim.x*blockDim.x){
    const float* row = Vb + at*4*12;
    a0 += sspf(row[0]);  a1 += sspf(row[12]);
    a2 += sspf(row[24]); a3 += sspf(row[36]);
  }
  atomicAdd(&sE[0],a0); atomicAdd(&sE[1],a1);
  atomicAdd(&sE[2],a2); atomicAdd(&sE[3],a3);
  __syncthreads();
  if (t<4) atomicAdd(&Eacc[t], sE[t]);
}

__global__ void final_dense_kernel(const float* __restrict__ Eacc,
    const float* __restrict__ w1,const float* __restrict__ b1,
    const float* __restrict__ w2,const float* __restrict__ b2,
    const float* __restrict__ w3,const float* __restrict__ b3,
    float* __restrict__ out)
{
  __shared__ float sE1[4];
  __shared__ float sH[256];
  const int t=threadIdx.x;
  if (t<4){
    float v=b1[t];
    #pragma unroll
    for (int j=0;j<4;j++) v += w1[t*4+j]*Eacc[j];
    sE1[t] = (v>0.f)? v : expm1f(v);
  }
  __syncthreads();
  {
    float v=b2[t];
    #pragma unroll
    for (int j=0;j<4;j++) v += w2[t*4+j]*sE1[j];
    sH[t]=v;
  }
  __syncthreads();
  if (t==0){
    float s=b3[0];
    for (int j=0;j<256;j++) s += w3[j]*sH[j];
    out[0]=s;
  }
}

// ---------------- launcher ----------------
extern "C" void kernel_launch(void* const* d_in, const int* in_sizes, int n_in,
                              void* d_out, int out_size, void* d_ws, size_t ws_size,
                              hipStream_t stream)
{
  const int* atom_types = (const int*)d_in[0];
  const int* nei_idx    = (const int*)d_in[1];
  const float* nei_vec  = (const float*)d_in[2];
  const float* in_f[36];
  for (int i=0;i<36 && i<n_in;i++) in_f[i] = (const float*)d_in[i];
  const int N = in_sizes[0];

  const i64 bsz = (i64)N*24*12;
  const size_t needed = 8192 + (size_t)3*bsz*4;
  if (ws_size < needed) return;

  char* ws = (char*)d_ws;
  float* cg   = (float*)ws;
  float* accs = (float*)(ws + 4096);
  float* gs1 = accs; float* gs2 = accs+48; float* gs3 = accs+72; float* Eacc = accs+80;
  float* bufA = (float*)(ws + 8192);
  float* bufB = bufA + bsz;
  float* bufC = bufB + bsz;

  #define LP(l, j) in_f[3 + 9*(l) + (j)]
  hipMemsetAsync(accs, 0, 512, stream);
  cg_init_kernel<<<15, 64, 0, stream>>>(cg);

  // ---- layer 1 (C=24, A=8, T=768, HCH=2) ----
  siA1_kernel<<<(N*24+255)/256, 256, 0, stream>>>(atom_types, LP(0,0), LP(0,1), bufB, N);
  conv_kernel<24,8,768,2><<<(N+7)/8, 768, 0, stream>>>(bufB, nei_idx, nei_vec,
      LP(0,2),LP(0,3),LP(0,4),LP(0,5), cg, bufC, N);
  normsiB_kernel<24><<<2048,64,0,stream>>>(bufC, LP(0,6), LP(0,7), bufA, gs1, N);
  // ---- layer 2 (C=12, A=16, T=768, HCH=4) ----
  siaNL_kernel<24,12><<<2048,64,0,stream>>>(bufA, gs1, LP(0,8), LP(1,0), LP(1,1), bufB, N);
  conv_kernel<12,16,768,4><<<(N+15)/16, 768, 0, stream>>>(bufB, nei_idx, nei_vec,
      LP(1,2),LP(1,3),LP(1,4),LP(1,5), cg, bufC, N);
  normsiB_kernel<12><<<2048,64,0,stream>>>(bufC, LP(1,6), LP(1,7), bufA, gs2, N);
  // ---- layer 3 (C=4, A=16, T=256, HCH=16) ----
  siaNL_kernel<12,4><<<2048,64,0,stream>>>(bufA, gs2, LP(1,8), LP(2,0), LP(2,1), bufB, N);
  conv_kernel<4,16,256,16><<<(N+15)/16, 256, 0, stream>>>(bufB, nei_idx, nei_vec,
      LP(2,2),LP(2,3),LP(2,4),LP(2,5), cg, bufC, N);
  normsiB_kernel<4><<<2048,64,0,stream>>>(bufC, LP(2,6), LP(2,7), bufA, gs3, N);
  // ---- readout ----
  final_reduce_kernel<<<128,256,0,stream>>>(bufA, Eacc, N);
  final_dense_kernel<<<1,256,0,stream>>>(Eacc, in_f[30],in_f[31],in_f[32],in_f[33],in_f[34],in_f[35],
                                         (float*)d_out);
  #undef LP
}

// Round 7
// 4281.301 us; speedup vs baseline: 1.1135x; 1.1135x over previous
//
#include <hip/hip_runtime.h>
#include <math.h>

typedef long long i64;

#define EPSF 1e-8f

// ---------------- path metadata ----------------
constexpr int NPATH = 15;
constexpr int PI_[NPATH] = {0,0,1,1,1,1,0,1,1,2,2,2,2,2,2};
constexpr int PF_[NPATH] = {0,1,0,1,1,1,2,2,2,2,2,2,0,1,1};
constexpr int PO_[NPATH] = {0,1,1,0,1,2,2,1,2,0,1,2,2,1,2};
constexpr int ISZ[NPATH] = {1,1,3,3,3,3,1,3,3,5,5,5,5,5,5};
constexpr int FSZ[NPATH] = {1,3,1,3,3,3,5,5,5,5,5,5,1,3,3};
constexpr int OSZ[NPATH] = {1,3,3,1,3,5,5,3,5,1,3,5,5,3,5};
constexpr int IBASE[NPATH] = {0,0,1,1,1,1,0,1,1,4,4,4,4,4,4};
constexpr int FBASE[NPATH] = {0,1,0,1,1,1,4,4,4,4,4,4,0,1,1};
constexpr int OBASE[NPATH] = {0,1,1,0,1,4,4,1,4,0,1,4,4,1,4};
constexpr int CGOFF[NPATH+1] = {0,1,10,19,28,55,100,125,170,245,270,345,470,495,540,615};
constexpr int CGTOT = 615;

// path-group tables (wave-uniform dispatch; balanced acc+w2 register load)
constexpr int gcnt4[4]    = {5,4,3,3};
constexpr int gpath4[4][5]= {{0,1,2,3,4},{5,6,7,8,0},{9,10,12,0,0},{11,13,14,0,0}};
constexpr int gcnt8[8]    = {1,1,1,2,2,2,3,3};
constexpr int gpath8[8][3]= {{9,0,0},{10,0,0},{11,0,0},{7,8,0},{13,14,0},{3,4,0},{5,6,12},{0,1,2}};

constexpr int psize(int p){ return ISZ[p]*FSZ[p]; }
constexpr int gcntf(int PG,int G){ return PG==4 ? gcnt4[G] : gcnt8[G]; }
constexpr int gpathf(int PG,int G,int I){ return PG==4 ? gpath4[G][I] : gpath8[G][I]; }
constexpr int laccf(int PG,int G,int I){
  int s=0; for (int i=0;i<I;++i) s += psize(gpathf(PG,G,i)); return s;
}

// ---------------- CG init (device-side, mirrors reference _su2_cg/_q) ----------------
__device__ double dfact(int n){ double r=1.0; for(int i=2;i<=n;++i) r*=(double)i; return r; }

__device__ double su2cg(int j1,int m1,int j2,int m2,int j3,int m3){
  if (m1+m2 != m3) return 0.0;
  int vmin = max(max(-j1+j2+m3, -j1+m1), 0);
  int vmax = min(min(j2+j3+m1, j3-j1+j2), j3+m3);
  if (vmax < vmin) return 0.0;
  double c = sqrt((double)(2*j3+1) * dfact(j3+j1-j2)*dfact(j3-j1+j2)*dfact(j1+j2-j3)
                  * dfact(j3+m3)*dfact(j3-m3)
                  / (dfact(j1+j2+j3+1)*dfact(j1-m1)*dfact(j1+m1)*dfact(j2-m2)*dfact(j2+m2)));
  double s = 0.0;
  for (int v=vmin; v<=vmax; ++v){
    double t = dfact(j2+j3+m1-v)*dfact(j1-m1+v)
             / (dfact(v)*dfact(j3-j1+j2-v)*dfact(j3+m3-v)*dfact(j1-j2-m3+v));
    s += ((v+j2+m2)&1) ? -t : t;
  }
  return c*s;
}

__device__ void qmat_lds(int l, double* qr, double* qi){
  for (int e=0;e<25;e++){ qr[e]=0.0; qi[e]=0.0; }
  const double s2 = 0.70710678118654752440;
  for (int m=-l; m<0; ++m){
    qr[(l+m)*5 + (l-m)] = s2;
    qi[(l+m)*5 + (l+m)] = -s2;
  }
  qr[l*5+l] = 1.0;
  for (int m=1; m<=l; ++m){
    double sg = (m&1)? -1.0 : 1.0;
    qr[(l+m)*5 + (l+m)] = sg*s2;
    qi[(l+m)*5 + (l-m)] = sg*s2;
  }
  if (l==1){
    for (int e=0;e<25;e++){ double r=qr[e], m=qi[e]; qr[e]=m; qi[e]=-r; }
  } else if (l==2){
    for (int e=0;e<25;e++){ qr[e]=-qr[e]; qi[e]=-qi[e]; }
  }
}

__global__ void cg_init_kernel(float* __restrict__ cg){
  int p = blockIdx.x;
  int li = PI_[p], lf = PF_[p], lo = PO_[p];
  int isz = 2*li+1, fsz = 2*lf+1, osz = 2*lo+1;
  __shared__ double sC[125];
  __shared__ double qir[25],qii[25],qfr[25],qfi[25],qor[25],qoi[25];
  if (threadIdx.x==0){
    qmat_lds(li,qir,qii); qmat_lds(lf,qfr,qfi); qmat_lds(lo,qor,qoi);
  }
  int tot = isz*fsz*osz;
  for (int e=threadIdx.x; e<tot; e+=blockDim.x){
    int a = e/(fsz*osz); int r = e%(fsz*osz); int b = r/osz; int n = r%osz;
    sC[e] = su2cg(li, a-li, lf, b-lf, lo, n-lo);
  }
  __syncthreads();
  for (int e=threadIdx.x; e<tot; e+=blockDim.x){
    int mo = e/(isz*fsz); int r = e%(isz*fsz); int ji = r/fsz; int lff = r%fsz;
    double acc = 0.0;
    for (int a=0;a<isz;a++) for(int b=0;b<fsz;b++) for(int n=0;n<osz;n++){
      double s = sC[(a*fsz+b)*osz+n];
      if (s==0.0) continue;
      double r1=qir[a*5+ji],  m1=qii[a*5+ji];
      double r2=qfr[b*5+lff], m2=qfi[b*5+lff];
      double r3=qor[n*5+mo],  m3=-qoi[n*5+mo];
      double rr = r1*r2 - m1*m2;
      double mm = r1*m2 + m1*r2;
      acc += (rr*r3 - mm*m3)*s;
    }
    cg[CGOFF[p] + (mo*isz+ji)*fsz + lff] = (float)acc;
  }
}

// ---------------- helpers ----------------
__device__ __forceinline__ float sspf(float x){
  float sp = (x > 20.f) ? x : log1pf(__expf(x));
  return sp - 0.69314718055994531f;
}

// ---------------- layer-1 self-interaction (one-hot input) ----------------
__global__ void siA1_kernel(const int* __restrict__ types, const float* __restrict__ w,
                            const float* __restrict__ b, float* __restrict__ Vp, int N){
  int idx = blockIdx.x*blockDim.x + threadIdx.x;
  if (idx >= N*24) return;
  int n = idx/24, d = idx%24;
  float v = w[d*3 + types[n]] + b[d];
  float* row = Vp + (i64)idx*12;
  row[0] = v;
  #pragma unroll
  for (int m=1;m<12;m++) row[m]=0.f;
}

// =====================================================================
// conv kernel, cif-factored with PG wave-aligned path-groups.
// Per k: acc[i][f] += (w2.h) * Y[f] * Vg[i] in registers; CG applied once
// in the epilogue. w2 rows live in registers (SCALAR loads/stores only —
// no float4 punning into private arrays; R2/R3/R6 spill lesson).
// =====================================================================

template<int PG,int G,int I,int C>
__device__ __forceinline__ void loadw2G(const float* __restrict__ gw2, const float* __restrict__ gb2,
                                        int c, float* __restrict__ w2r, float* __restrict__ b2r){
  if constexpr (I < gcntf(PG,G)){
    constexpr int P = gpathf(PG,G,I);
    #pragma unroll
    for (int j=0;j<12;++j) w2r[I*12+j] = gw2[(P*C+c)*12+j];
    b2r[I] = gb2[P*C+c];
    loadw2G<PG,G,I+1,C>(gw2,gb2,c,w2r,b2r);
  }
}

template<int PG,int G,int I>
__device__ __forceinline__ void ipathsG(const float* __restrict__ w2r, const float* __restrict__ b2r,
                                        const float* __restrict__ sha, const float* __restrict__ yv,
                                        const float* __restrict__ vgv, float* __restrict__ accR){
  if constexpr (I < gcntf(PG,G)){
    constexpr int P = gpathf(PG,G,I);
    constexpr int LO = laccf(PG,G,I);
    const float* h = sha + P*12;
    float4 h0 = *reinterpret_cast<const float4*>(h);
    float4 h1 = *reinterpret_cast<const float4*>(h+4);
    float4 h2 = *reinterpret_cast<const float4*>(h+8);
    float rr = b2r[I]
      + w2r[I*12+0]*h0.x + w2r[I*12+1]*h0.y + w2r[I*12+2]*h0.z + w2r[I*12+3]*h0.w
      + w2r[I*12+4]*h1.x + w2r[I*12+5]*h1.y + w2r[I*12+6]*h1.z + w2r[I*12+7]*h1.w
      + w2r[I*12+8]*h2.x + w2r[I*12+9]*h2.y + w2r[I*12+10]*h2.z + w2r[I*12+11]*h2.w;
    float ry[5];
    #pragma unroll
    for (int f=0; f<FSZ[P]; ++f) ry[f] = rr * yv[FBASE[P]+f];
    #pragma unroll
    for (int i=0; i<ISZ[P]; ++i){
      const float vv = vgv[IBASE[P]+i];
      #pragma unroll
      for (int f=0; f<FSZ[P]; ++f) accR[LO + i*FSZ[P] + f] += ry[f]*vv;
    }
    ipathsG<PG,G,I+1>(w2r,b2r,sha,yv,vgv,accR);
  }
}

template<int PG,int G,int I>
__device__ __forceinline__ void epathsG(const float* __restrict__ accR, const float* __restrict__ sCG,
                                        float* __restrict__ o){
  if constexpr (I < gcntf(PG,G)){
    constexpr int P = gpathf(PG,G,I);
    constexpr int LO = laccf(PG,G,I);
    #pragma unroll
    for (int om=0; om<OSZ[P]; ++om){
      float s = 0.f;
      #pragma unroll
      for (int i=0; i<ISZ[P]; ++i){
        #pragma unroll
        for (int f=0; f<FSZ[P]; ++f)
          s += sCG[CGOFF[P] + (om*ISZ[P]+i)*FSZ[P] + f] * accR[LO + i*FSZ[P] + f];
      }
      o[OBASE[P]+om] += s;
    }
    epathsG<PG,G,I+1>(accR,sCG,o);
  }
}

template<int C, int A, int PG, int T>
__global__ __launch_bounds__(T) void conv_kernel(
    const float* __restrict__ Vp, const int* __restrict__ nei_idx, const float* __restrict__ nei_vec,
    const float* __restrict__ gw1, const float* __restrict__ gb1,
    const float* __restrict__ gw2, const float* __restrict__ gb2,
    const float* __restrict__ cg, float* __restrict__ O, int N)
{
  constexpr int GRP = A*C;
  static_assert(PG*GRP == T, "bad geometry");
  static_assert(GRP % 64 == 0, "path group not wave-aligned");
  constexpr int ACCMX = (PG==4) ? 55 : 30;
  constexpr int W2MX  = (PG==4) ? 5 : 3;
  constexpr int SHSZ  = (A*180 > GRP*9) ? A*180 : GRP*9;

  __shared__ float sw1c[2160];          // chunked: [(q*180+row)*4+jj]
  __shared__ float sb1[180];
  __shared__ float sCG[CGTOT];
  __shared__ float srbf[2][A*12];
  __shared__ float sYs[2][A*12];
  __shared__ int   snei[A*33];          // stride 33: bank-spread
  __shared__ float sh[SHSZ];            // h rows (stride 180); reused for group-reduce

  const int t = threadIdx.x;
  const i64 atom0 = (i64)blockIdx.x * A;
  const int pg  = t / GRP;              // wave-uniform
  const int rem = t - pg*GRP;
  const int a = rem / C;
  const int c = rem % C;

  for (int e=t; e<2160; e+=T){
    int row = e/12, j = e - row*12;
    sw1c[((j>>2)*180 + row)*4 + (j&3)] = gw1[e];
  }
  for (int e=t; e<180;   e+=T) sb1[e]=gb1[e];
  for (int e=t; e<CGTOT; e+=T) sCG[e]=cg[e];
  for (int e=t; e<A*32;  e+=T){
    int aa=e>>5, kk=e&31;
    i64 at=atom0+aa; if (at>=(i64)N) at=N-1;
    snei[aa*33+kk] = nei_idx[at*32+kk];
  }

  // my path-group's w2 rows -> registers (scalar stores only)
  float w2r[W2MX*12];
  float b2r[W2MX];
  if constexpr (PG==4){
    if      (pg==0) loadw2G<4,0,0,C>(gw2,gb2,c,w2r,b2r);
    else if (pg==1) loadw2G<4,1,0,C>(gw2,gb2,c,w2r,b2r);
    else if (pg==2) loadw2G<4,2,0,C>(gw2,gb2,c,w2r,b2r);
    else            loadw2G<4,3,0,C>(gw2,gb2,c,w2r,b2r);
  } else {
    if      (pg==0) loadw2G<8,0,0,C>(gw2,gb2,c,w2r,b2r);
    else if (pg==1) loadw2G<8,1,0,C>(gw2,gb2,c,w2r,b2r);
    else if (pg==2) loadw2G<8,2,0,C>(gw2,gb2,c,w2r,b2r);
    else if (pg==3) loadw2G<8,3,0,C>(gw2,gb2,c,w2r,b2r);
    else if (pg==4) loadw2G<8,4,0,C>(gw2,gb2,c,w2r,b2r);
    else if (pg==5) loadw2G<8,5,0,C>(gw2,gb2,c,w2r,b2r);
    else if (pg==6) loadw2G<8,6,0,C>(gw2,gb2,c,w2r,b2r);
    else            loadw2G<8,7,0,C>(gw2,gb2,c,w2r,b2r);
  }

  float accR[ACCMX];
  #pragma unroll
  for (int e=0;e<ACCMX;++e) accR[e]=0.f;

  auto stage = [&](int kn){
    const int buf = kn & 1;
    if (t < A*12){
      int aa = t/12, j = t - aa*12;
      i64 at = atom0 + aa; if (at >= (i64)N) at = N-1;
      const float* vv = &nei_vec[(at*32 + kn)*3];
      float x=vv[0], y=vv[1], z=vv[2];
      float d = sqrtf(fmaxf(x*x+y*y+z*z, EPSF));
      float dd = d - 0.72727272727272727f*(float)j;
      srbf[buf][t] = __expf(-dd*dd);
    }
    if (t < A){
      i64 at = atom0 + t; if (at >= (i64)N) at = N-1;
      const float* vv = &nei_vec[(at*32 + kn)*3];
      float x=vv[0], y=vv[1], z=vv[2];
      float r2 = fmaxf(x*x+y*y+z*z, EPSF);
      float inv = 1.f/r2;
      float* Ye = &sYs[buf][t*12];
      Ye[0]=1.f; Ye[1]=x; Ye[2]=y; Ye[3]=z;
      Ye[4]=x*y*inv; Ye[5]=y*z*inv;
      Ye[6]=(2.f*z*z - x*x - y*y)*(0.28867513459481287f*inv);
      Ye[7]=z*x*inv; Ye[8]=(x*x - y*y)*(0.5f*inv);
      Ye[9]=0.f; Ye[10]=0.f; Ye[11]=0.f;
    }
  };

  stage(0);
  __syncthreads();

  for (int k=0; k<32; ++k){
    const int buf = k & 1;
    // ---- h phase: h = relu(W1.rbf+b1); w1 chunked (conflict-free b128) ----
    for (int e=t; e<A*180; e+=T){
      int row = e%180, aa = e/180;
      float4 w0 = *reinterpret_cast<const float4*>(&sw1c[row*4]);
      float4 w1 = *reinterpret_cast<const float4*>(&sw1c[(180+row)*4]);
      float4 w2v= *reinterpret_cast<const float4*>(&sw1c[(360+row)*4]);
      const float* rb = &srbf[buf][aa*12];
      float4 r0 = *reinterpret_cast<const float4*>(rb);
      float4 r1 = *reinterpret_cast<const float4*>(rb+4);
      float4 r2 = *reinterpret_cast<const float4*>(rb+8);
      float v = sb1[row]
        + w0.x*r0.x + w0.y*r0.y + w0.z*r0.z + w0.w*r0.w
        + w1.x*r1.x + w1.y*r1.y + w1.z*r1.z + w1.w*r1.w
        + w2v.x*r2.x + w2v.y*r2.y + w2v.z*r2.z + w2v.w*r2.w;
      sh[aa*180 + row] = fmaxf(v, 0.f);
    }
    if (k+1 < 32) stage(k+1);
    __syncthreads();
    // ---- inner: r-dot from (w2 regs, h LDS) then cif outer-product ----
    {
      const int nei = snei[a*33 + k];
      const float* vr = &Vp[((i64)nei*C + c)*12];
      float4 va = *reinterpret_cast<const float4*>(vr);
      float4 vb = *reinterpret_cast<const float4*>(vr+4);
      float v8 = vr[8];
      float vgv[9] = {va.x,va.y,va.z,va.w, vb.x,vb.y,vb.z,vb.w, v8};
      const float* Yb = &sYs[buf][a*12];
      float4 ya = *reinterpret_cast<const float4*>(Yb);
      float4 yb = *reinterpret_cast<const float4*>(Yb+4);
      float y8 = Yb[8];
      float yv[9] = {ya.x,ya.y,ya.z,ya.w, yb.x,yb.y,yb.z,yb.w, y8};
      const float* sha = &sh[a*180];
      if constexpr (PG==4){
        if      (pg==0) ipathsG<4,0,0>(w2r,b2r,sha,yv,vgv,accR);
        else if (pg==1) ipathsG<4,1,0>(w2r,b2r,sha,yv,vgv,accR);
        else if (pg==2) ipathsG<4,2,0>(w2r,b2r,sha,yv,vgv,accR);
        else            ipathsG<4,3,0>(w2r,b2r,sha,yv,vgv,accR);
      } else {
        if      (pg==0) ipathsG<8,0,0>(w2r,b2r,sha,yv,vgv,accR);
        else if (pg==1) ipathsG<8,1,0>(w2r,b2r,sha,yv,vgv,accR);
        else if (pg==2) ipathsG<8,2,0>(w2r,b2r,sha,yv,vgv,accR);
        else if (pg==3) ipathsG<8,3,0>(w2r,b2r,sha,yv,vgv,accR);
        else if (pg==4) ipathsG<8,4,0>(w2r,b2r,sha,yv,vgv,accR);
        else if (pg==5) ipathsG<8,5,0>(w2r,b2r,sha,yv,vgv,accR);
        else if (pg==6) ipathsG<8,6,0>(w2r,b2r,sha,yv,vgv,accR);
        else            ipathsG<8,7,0>(w2r,b2r,sha,yv,vgv,accR);
      }
    }
    __syncthreads();
  }

  // ---- epilogue: CG contraction once; sequential cross-group reduce ----
  float o[9];
  #pragma unroll
  for (int m=0;m<9;++m) o[m]=0.f;
  if constexpr (PG==4){
    if      (pg==0) epathsG<4,0,0>(accR,sCG,o);
    else if (pg==1) epathsG<4,1,0>(accR,sCG,o);
    else if (pg==2) epathsG<4,2,0>(accR,sCG,o);
    else            epathsG<4,3,0>(accR,sCG,o);
  } else {
    if      (pg==0) epathsG<8,0,0>(accR,sCG,o);
    else if (pg==1) epathsG<8,1,0>(accR,sCG,o);
    else if (pg==2) epathsG<8,2,0>(accR,sCG,o);
    else if (pg==3) epathsG<8,3,0>(accR,sCG,o);
    else if (pg==4) epathsG<8,4,0>(accR,sCG,o);
    else if (pg==5) epathsG<8,5,0>(accR,sCG,o);
    else if (pg==6) epathsG<8,6,0>(accR,sCG,o);
    else            epathsG<8,7,0>(accR,sCG,o);
  }

  #pragma unroll
  for (int g=1; g<PG; ++g){
    __syncthreads();
    if (pg==g){
      #pragma unroll
      for (int m=0;m<9;++m) sh[rem*9+m]=o[m];
    }
    __syncthreads();
    if (pg==0){
      #pragma unroll
      for (int m=0;m<9;++m) o[m] += sh[rem*9+m];
    }
  }

  i64 at = atom0 + a;
  if (pg==0 && at < (i64)N){
    float* orow = O + (at*C + c)*12;
    *reinterpret_cast<float4*>(orow)   = make_float4(o[0],o[1],o[2],o[3]);
    *reinterpret_cast<float4*>(orow+4) = make_float4(o[4],o[5],o[6],o[7]);
    orow[8] = o[8];
  }
}

// ---------------- per-atom norm + siB + per-channel global sums ----------------
template<int C>
__global__ __launch_bounds__(64) void normsiB_kernel(
    const float* __restrict__ O, const float* __restrict__ w, const float* __restrict__ b,
    float* __restrict__ Vb, float* __restrict__ gsum, int N)
{
  __shared__ float sW[C*C];
  __shared__ float sO[C*9];
  __shared__ float sg[2*C];
  const int t = threadIdx.x;
  for (int e=t; e<C*C; e+=64) sW[e]=w[e];
  for (int e=t; e<2*C; e+=64) sg[e]=0.f;
  __syncthreads();
  const int iters = (N + gridDim.x - 1)/gridDim.x;
  for (int it=0; it<iters; ++it){
    i64 at = (i64)blockIdx.x + (i64)it*gridDim.x;
    float p0=0.f,p1=0.f,p2=0.f;
    if (at<(i64)N){
      for (int e=t; e<C*9; e+=64){
        int cc=e/9, m=e-cc*9;
        float v = O[((i64)at*C+cc)*12+m];
        sO[e]=v;
        float vv=v*v;
        if (m==0) p0+=vv; else if (m<4) p1+=vv; else p2+=vv;
      }
    }
    #pragma unroll
    for (int off=1; off<64; off<<=1){
      p0 += __shfl_xor(p0, off);
      p1 += __shfl_xor(p1, off);
      p2 += __shfl_xor(p2, off);
    }
    float i0 = 1.f/sqrtf(fmaxf(p0, EPSF));
    float i1 = 1.f/sqrtf(fmaxf(p1, EPSF));
    float i2 = 1.f/sqrtf(fmaxf(p2, EPSF));
    __syncthreads();
    if (at<(i64)N){
      for (int e=t; e<C*9; e+=64){
        int d=e/9, m=e-d*9;
        float inv = (m==0)? i0 : (m<4)? i1 : i2;
        const float* wr = &sW[d*C];
        float s=0.f;
        #pragma unroll
        for (int cc=0; cc<C; ++cc) s += wr[cc]*sO[cc*9+m];
        float outv = s*inv + ((m==0)? b[d] : 0.f);
        Vb[((i64)at*C+d)*12+m]=outv;
        if (m>=1) atomicAdd(&sg[(m<4?0:1)*C + d], outv*outv);
      }
    }
    __syncthreads();
  }
  for (int e=t; e<2*C; e+=64) atomicAdd(&gsum[e], sg[e]);
}

// ---------------- fused nonlinearity + next-layer siA ----------------
template<int Ci, int Co>
__global__ __launch_bounds__(64) void siaNL_kernel(
    const float* __restrict__ Vb, const float* __restrict__ gsum, const float* __restrict__ nlb,
    const float* __restrict__ w, const float* __restrict__ b, float* __restrict__ Vp, int N)
{
  __shared__ float sW[Co*Ci];
  __shared__ float sIn[Ci*9];
  __shared__ float sT[2*Ci];
  const int t=threadIdx.x;
  for (int e=t; e<Co*Ci; e+=64) sW[e]=w[e];
  for (int e=t; e<2*Ci;  e+=64) sT[e] = sqrtf(gsum[e]) + nlb[e];
  __syncthreads();
  const int iters = (N + gridDim.x - 1)/gridDim.x;
  for (int it=0; it<iters; ++it){
    i64 at = (i64)blockIdx.x + (i64)it*gridDim.x;
    if (at<(i64)N){
      for (int e=t; e<Ci*9; e+=64){
        int cc=e/9, m=e-cc*9;
        float v = Vb[((i64)at*Ci+cc)*12+m];
        float x = (m==0)? sspf(v) : (m<4)? v*sT[cc] : v*sT[Ci+cc];
        sIn[e]=x;
      }
    }
    __syncthreads();
    if (at<(i64)N){
      for (int e=t; e<Co*9; e+=64){
        int d=e/9, m=e-d*9;
        const float* wr=&sW[d*Ci];
        float s = (m==0)? b[d] : 0.f;
        #pragma unroll
        for (int cc=0;cc<Ci;++cc) s += wr[cc]*sIn[cc*9+m];
        Vp[((i64)at*Co+d)*12+m]=s;
      }
    }
    __syncthreads();
  }
}

// ---------------- final readout ----------------
__global__ void final_reduce_kernel(const float* __restrict__ Vb, float* __restrict__ Eacc, int N){
  __shared__ float sE[4];
  const int t=threadIdx.x;
  if (t<4) sE[t]=0.f;
  __syncthreads();
  float a0=0.f,a1=0.f,a2=0.f,a3=0.f;
  for (i64 at = (i64)blockIdx.x*blockDim.x + t; at < (i64)N; at += (i64)gridDim.x*blockDim.x){
    const float* row = Vb + at*4*12;
    a0 += sspf(row[0]);  a1 += sspf(row[12]);
    a2 += sspf(row[24]); a3 += sspf(row[36]);
  }
  atomicAdd(&sE[0],a0); atomicAdd(&sE[1],a1);
  atomicAdd(&sE[2],a2); atomicAdd(&sE[3],a3);
  __syncthreads();
  if (t<4) atomicAdd(&Eacc[t], sE[t]);
}

__global__ void final_dense_kernel(const float* __restrict__ Eacc,
    const float* __restrict__ w1,const float* __restrict__ b1,
    const float* __restrict__ w2,const float* __restrict__ b2,
    const float* __restrict__ w3,const float* __restrict__ b3,
    float* __restrict__ out)
{
  __shared__ float sE1[4];
  __shared__ float sH[256];
  const int t=threadIdx.x;
  if (t<4){
    float v=b1[t];
    #pragma unroll
    for (int j=0;j<4;j++) v += w1[t*4+j]*Eacc[j];
    sE1[t] = (v>0.f)? v : expm1f(v);
  }
  __syncthreads();
  {
    float v=b2[t];
    #pragma unroll
    for (int j=0;j<4;j++) v += w2[t*4+j]*sE1[j];
    sH[t]=v;
  }
  __syncthreads();
  if (t==0){
    float s=b3[0];
    for (int j=0;j<256;j++) s += w3[j]*sH[j];
    out[0]=s;
  }
}

// ---------------- launcher ----------------
extern "C" void kernel_launch(void* const* d_in, const int* in_sizes, int n_in,
                              void* d_out, int out_size, void* d_ws, size_t ws_size,
                              hipStream_t stream)
{
  const int* atom_types = (const int*)d_in[0];
  const int* nei_idx    = (const int*)d_in[1];
  const float* nei_vec  = (const float*)d_in[2];
  const float* in_f[36];
  for (int i=0;i<36 && i<n_in;i++) in_f[i] = (const float*)d_in[i];
  const int N = in_sizes[0];

  const i64 bsz = (i64)N*24*12;
  const size_t needed = 8192 + (size_t)3*bsz*4;
  if (ws_size < needed) return;

  char* ws = (char*)d_ws;
  float* cg   = (float*)ws;
  float* accs = (float*)(ws + 4096);
  float* gs1 = accs; float* gs2 = accs+48; float* gs3 = accs+72; float* Eacc = accs+80;
  float* bufA = (float*)(ws + 8192);
  float* bufB = bufA + bsz;
  float* bufC = bufB + bsz;

  #define LP(l, j) in_f[3 + 9*(l) + (j)]
  hipMemsetAsync(accs, 0, 512, stream);
  cg_init_kernel<<<15, 64, 0, stream>>>(cg);

  // ---- layer 1 (C=24, A=8, PG=4, T=768) ----
  siA1_kernel<<<(N*24+255)/256, 256, 0, stream>>>(atom_types, LP(0,0), LP(0,1), bufB, N);
  conv_kernel<24,8,4,768><<<(N+7)/8, 768, 0, stream>>>(bufB, nei_idx, nei_vec,
      LP(0,2),LP(0,3),LP(0,4),LP(0,5), cg, bufC, N);
  normsiB_kernel<24><<<2048,64,0,stream>>>(bufC, LP(0,6), LP(0,7), bufA, gs1, N);
  // ---- layer 2 (C=12, A=16, PG=4, T=768) ----
  siaNL_kernel<24,12><<<2048,64,0,stream>>>(bufA, gs1, LP(0,8), LP(1,0), LP(1,1), bufB, N);
  conv_kernel<12,16,4,768><<<(N+15)/16, 768, 0, stream>>>(bufB, nei_idx, nei_vec,
      LP(1,2),LP(1,3),LP(1,4),LP(1,5), cg, bufC, N);
  normsiB_kernel<12><<<2048,64,0,stream>>>(bufC, LP(1,6), LP(1,7), bufA, gs2, N);
  // ---- layer 3 (C=4, A=16, PG=8, T=512) ----
  siaNL_kernel<12,4><<<2048,64,0,stream>>>(bufA, gs2, LP(1,8), LP(2,0), LP(2,1), bufB, N);
  conv_kernel<4,16,8,512><<<(N+15)/16, 512, 0, stream>>>(bufB, nei_idx, nei_vec,
      LP(2,2),LP(2,3),LP(2,4),LP(2,5), cg, bufC, N);
  normsiB_kernel<4><<<2048,64,0,stream>>>(bufC, LP(2,6), LP(2,7), bufA, gs3, N);
  // ---- readout ----
  final_reduce_kernel<<<128,256,0,stream>>>(bufA, Eacc, N);
  final_dense_kernel<<<1,256,0,stream>>>(Eacc, in_f[30],in_f[31],in_f[32],in_f[33],in_f[34],in_f[35],
                                         (float*)d_out);
  #undef LP
}

// Round 8
// 2201.206 us; speedup vs baseline: 2.1658x; 1.9450x over previous
//
#include <hip/hip_runtime.h>
#include <math.h>

typedef long long i64;

#define EPSF 1e-8f

// ---------------- path metadata ----------------
constexpr int NPATH = 15;
constexpr int PI_[NPATH] = {0,0,1,1,1,1,0,1,1,2,2,2,2,2,2};
constexpr int PF_[NPATH] = {0,1,0,1,1,1,2,2,2,2,2,2,0,1,1};
constexpr int PO_[NPATH] = {0,1,1,0,1,2,2,1,2,0,1,2,2,1,2};
constexpr int ISZ[NPATH] = {1,1,3,3,3,3,1,3,3,5,5,5,5,5,5};
constexpr int FSZ[NPATH] = {1,3,1,3,3,3,5,5,5,5,5,5,1,3,3};
constexpr int OSZ[NPATH] = {1,3,3,1,3,5,5,3,5,1,3,5,5,3,5};
constexpr int IBASE[NPATH] = {0,0,1,1,1,1,0,1,1,4,4,4,4,4,4};
constexpr int FBASE[NPATH] = {0,1,0,1,1,1,4,4,4,4,4,4,0,1,1};
constexpr int OBASE[NPATH] = {0,1,1,0,1,4,4,1,4,0,1,4,4,1,4};
constexpr int CGOFF[NPATH+1] = {0,1,10,19,28,55,100,125,170,245,270,345,470,495,540,615};
// float4-padded per-(a,k) G offsets (each path's OSZ*ISZ block padded to mult of 4)
constexpr int GPOFF[NPATH+1] = {0,4,8,20,24,36,52,60,72,88,96,112,140,168,184,212};
constexpr int CGTOT = 615;
constexpr int GPTOT = 212;

// ---------------- CG init (device-side, mirrors reference _su2_cg/_q) ----------------
__device__ double dfact(int n){ double r=1.0; for(int i=2;i<=n;++i) r*=(double)i; return r; }

__device__ double su2cg(int j1,int m1,int j2,int m2,int j3,int m3){
  if (m1+m2 != m3) return 0.0;
  int vmin = max(max(-j1+j2+m3, -j1+m1), 0);
  int vmax = min(min(j2+j3+m1, j3-j1+j2), j3+m3);
  if (vmax < vmin) return 0.0;
  double c = sqrt((double)(2*j3+1) * dfact(j3+j1-j2)*dfact(j3-j1+j2)*dfact(j1+j2-j3)
                  * dfact(j3+m3)*dfact(j3-m3)
                  / (dfact(j1+j2+j3+1)*dfact(j1-m1)*dfact(j1+m1)*dfact(j2-m2)*dfact(j2+m2)));
  double s = 0.0;
  for (int v=vmin; v<=vmax; ++v){
    double t = dfact(j2+j3+m1-v)*dfact(j1-m1+v)
             / (dfact(v)*dfact(j3-j1+j2-v)*dfact(j3+m3-v)*dfact(j1-j2-m3+v));
    s += ((v+j2+m2)&1) ? -t : t;
  }
  return c*s;
}

__device__ void qmat_lds(int l, double* qr, double* qi){
  for (int e=0;e<25;e++){ qr[e]=0.0; qi[e]=0.0; }
  const double s2 = 0.70710678118654752440;
  for (int m=-l; m<0; ++m){
    qr[(l+m)*5 + (l-m)] = s2;
    qi[(l+m)*5 + (l+m)] = -s2;
  }
  qr[l*5+l] = 1.0;
  for (int m=1; m<=l; ++m){
    double sg = (m&1)? -1.0 : 1.0;
    qr[(l+m)*5 + (l+m)] = sg*s2;
    qi[(l+m)*5 + (l-m)] = sg*s2;
  }
  if (l==1){
    for (int e=0;e<25;e++){ double r=qr[e], m=qi[e]; qr[e]=m; qi[e]=-r; }
  } else if (l==2){
    for (int e=0;e<25;e++){ qr[e]=-qr[e]; qi[e]=-qi[e]; }
  }
}

__global__ void cg_init_kernel(float* __restrict__ cg){
  int p = blockIdx.x;
  int li = PI_[p], lf = PF_[p], lo = PO_[p];
  int isz = 2*li+1, fsz = 2*lf+1, osz = 2*lo+1;
  __shared__ double sC[125];
  __shared__ double qir[25],qii[25],qfr[25],qfi[25],qor[25],qoi[25];
  if (threadIdx.x==0){
    qmat_lds(li,qir,qii); qmat_lds(lf,qfr,qfi); qmat_lds(lo,qor,qoi);
  }
  int tot = isz*fsz*osz;
  for (int e=threadIdx.x; e<tot; e+=blockDim.x){
    int a = e/(fsz*osz); int r = e%(fsz*osz); int b = r/osz; int n = r%osz;
    sC[e] = su2cg(li, a-li, lf, b-lf, lo, n-lo);
  }
  __syncthreads();
  for (int e=threadIdx.x; e<tot; e+=blockDim.x){
    int mo = e/(isz*fsz); int r = e%(isz*fsz); int ji = r/fsz; int lff = r%fsz;
    double acc = 0.0;
    for (int a=0;a<isz;a++) for(int b=0;b<fsz;b++) for(int n=0;n<osz;n++){
      double s = sC[(a*fsz+b)*osz+n];
      if (s==0.0) continue;
      double r1=qir[a*5+ji],  m1=qii[a*5+ji];
      double r2=qfr[b*5+lff], m2=qfi[b*5+lff];
      double r3=qor[n*5+mo],  m3=-qoi[n*5+mo];
      double rr = r1*r2 - m1*m2;
      double mm = r1*m2 + m1*r2;
      acc += (rr*r3 - mm*m3)*s;
    }
    cg[CGOFF[p] + (mo*isz+ji)*fsz + lff] = (float)acc;
  }
}

// ---------------- helpers ----------------
__device__ __forceinline__ float sspf(float x){
  float sp = (x > 20.f) ? x : log1pf(__expf(x));
  return sp - 0.69314718055994531f;
}

// ---------------- layer-1 self-interaction (one-hot input) ----------------
__global__ void siA1_kernel(const int* __restrict__ types, const float* __restrict__ w,
                            const float* __restrict__ b, float* __restrict__ Vp, int N){
  int idx = blockIdx.x*blockDim.x + threadIdx.x;
  if (idx >= N*24) return;
  int n = idx/24, d = idx%24;
  float v = w[d*3 + types[n]] + b[d];
  float* row = Vp + (i64)idx*12;
  row[0] = v;
  #pragma unroll
  for (int m=1;m<12;m++) row[m]=0.f;
}

// =====================================================================
// conv kernel (R4 structure, proven no-spill) with CHUNKED weight layouts:
// sw1c/sw2c stored as [(q*NROWS+row)*4+jj] so lane->row reads are 16B-stride
// canonical conflict-free ds_read_b128 (R4's 48B stride was 8-way conflicted).
// Per k: {h-phase + G-phase} sync {stage(k+1) + inner} sync.
// =====================================================================

// per-path G = CG.Y into padded-float4 layout
template<int A, int P>
__device__ __forceinline__ void gphase(int t, const float* __restrict__ sY,
                                       const float* __restrict__ sCG, float* __restrict__ sG){
  if constexpr (P < NPATH){
    constexpr int gsz = OSZ[P]*ISZ[P];
    for (int e=t; e<gsz*A; e+=192){
      int a = e % A, rel = e / A;
      const float* cr = &sCG[CGOFF[P] + rel*FSZ[P]];
      const float* Yr = &sY[a*12 + FBASE[P]];
      float v = 0.f;
      #pragma unroll
      for (int f=0; f<FSZ[P]; ++f) v += cr[f]*Yr[f];
      sG[a*GPTOT + GPOFF[P] + rel] = v;
    }
    gphase<A,P+1>(t,sY,sCG,sG);
  }
}

// G-stream: consume padded G via float4, 1 LDS read : 4 FMA, no arrays
template<int P, int V>
__device__ __forceinline__ void gstream(const float* __restrict__ sG_a,
                                        const float* vgr, float* acc){
  constexpr int gsz = OSZ[P]*ISZ[P];
  if constexpr (4*V < gsz){
    float4 g = *reinterpret_cast<const float4*>(&sG_a[GPOFF[P] + 4*V]);
    constexpr int e0 = 4*V;
    acc[OBASE[P] + (e0  )/ISZ[P]] += g.x * vgr[(e0  )%ISZ[P]];
    if constexpr (e0+1 < gsz) acc[OBASE[P] + (e0+1)/ISZ[P]] += g.y * vgr[(e0+1)%ISZ[P]];
    if constexpr (e0+2 < gsz) acc[OBASE[P] + (e0+2)/ISZ[P]] += g.z * vgr[(e0+2)%ISZ[P]];
    if constexpr (e0+3 < gsz) acc[OBASE[P] + (e0+3)/ISZ[P]] += g.w * vgr[(e0+3)%ISZ[P]];
    gstream<P,V+1>(sG_a,vgr,acc);
  }
}

// inner per-path: rr = b2 + w2.h (chunked LDS b128 both), fold, stream G
template<int C, int P, int PEND>
__device__ __forceinline__ void ipath(const float* __restrict__ sw2c, const float* __restrict__ sb2,
                                      int c, const float* __restrict__ sh_a,
                                      const float* __restrict__ sG_a,
                                      const float* vg, float* acc){
  if constexpr (P < PEND){
    constexpr int NR2 = 15*C;
    float4 w0 = *reinterpret_cast<const float4*>(&sw2c[(0*NR2 + P*C + c)*4]);
    float4 w1 = *reinterpret_cast<const float4*>(&sw2c[(1*NR2 + P*C + c)*4]);
    float4 w2v= *reinterpret_cast<const float4*>(&sw2c[(2*NR2 + P*C + c)*4]);
    const float* h = &sh_a[P*12];
    float4 h0 = *reinterpret_cast<const float4*>(h);
    float4 h1 = *reinterpret_cast<const float4*>(h+4);
    float4 h2 = *reinterpret_cast<const float4*>(h+8);
    float rr = sb2[P*C+c]
      + w0.x*h0.x + w0.y*h0.y + w0.z*h0.z + w0.w*h0.w
      + w1.x*h1.x + w1.y*h1.y + w1.z*h1.z + w1.w*h1.w
      + w2v.x*h2.x + w2v.y*h2.y + w2v.z*h2.z + w2v.w*h2.w;
    float vgr[5];
    #pragma unroll
    for (int i=0; i<ISZ[P]; ++i) vgr[i] = rr * vg[IBASE[P]+i];
    gstream<P,0>(sG_a, vgr, acc);
    ipath<C,P+1,PEND>(sw2c,sb2,c,sh_a,sG_a,vg,acc);
  }
}

template<int C, int A, int PG>
__global__ __launch_bounds__(192) void conv_kernel(
    const float* __restrict__ Vp, const int* __restrict__ nei_idx, const float* __restrict__ nei_vec,
    const float* __restrict__ gw1, const float* __restrict__ gb1,
    const float* __restrict__ gw2, const float* __restrict__ gb2,
    const float* __restrict__ cg, float* __restrict__ O, int N)
{
  constexpr int T = 192;
  constexpr int GRP = A*C;
  static_assert(PG*GRP == T, "bad geometry");
  constexpr int NR2 = 15*C;
  __shared__ float sw1c[2160];          // chunked: [(q*180+row)*4+jj]
  __shared__ float sb1[180];
  __shared__ float sw2c[NR2*12];        // chunked: [(q*NR2+row)*4+jj]
  __shared__ float sb2[NR2];
  __shared__ float sCG[CGTOT];
  __shared__ float srbf[A*12];
  __shared__ float sY[A*12];
  __shared__ float sh[A*180];
  __shared__ float sG[A*GPTOT];

  const int t = threadIdx.x;
  const i64 atom0 = (i64)blockIdx.x * A;

  for (int e=t; e<2160; e+=T){
    int row = e/12, j = e - row*12;
    sw1c[((j>>2)*180 + row)*4 + (j&3)] = gw1[e];
  }
  for (int e=t; e<180;   e+=T) sb1[e]=gb1[e];
  for (int e=t; e<NR2*12; e+=T){
    int row = e/12, j = e - row*12;
    sw2c[((j>>2)*NR2 + row)*4 + (j&3)] = gw2[e];
  }
  for (int e=t; e<NR2;   e+=T) sb2[e]=gb2[e];
  for (int e=t; e<CGTOT; e+=T) sCG[e]=cg[e];

  // stage rbf (A*12 threads, one exp each) + Y (A threads)
  auto stage = [&](int kn){
    if (t < A*12){
      int aa = t/12, j = t - aa*12;
      i64 at = atom0 + aa; if (at >= (i64)N) at = N-1;
      const float* vv = &nei_vec[(at*32 + kn)*3];
      float x=vv[0], y=vv[1], z=vv[2];
      float d = sqrtf(fmaxf(x*x+y*y+z*z, EPSF));
      float dd = d - 0.72727272727272727f*(float)j;
      srbf[t] = __expf(-dd*dd);
    }
    if (t < A){
      i64 at = atom0 + t; if (at >= (i64)N) at = N-1;
      const float* vv = &nei_vec[(at*32 + kn)*3];
      float x=vv[0], y=vv[1], z=vv[2];
      float r2 = fmaxf(x*x+y*y+z*z, EPSF);
      float inv = 1.f/r2;
      float* Ye = &sY[t*12];
      Ye[0]=1.f; Ye[1]=x; Ye[2]=y; Ye[3]=z;
      Ye[4]=x*y*inv; Ye[5]=y*z*inv;
      Ye[6]=(2.f*z*z - x*x - y*y)*(0.28867513459481287f*inv);
      Ye[7]=z*x*inv; Ye[8]=(x*x - y*y)*(0.5f*inv);
    }
  };

  stage(0);
  __syncthreads();

  // inner mapping: PG path groups x A atoms x C channels
  const int pg  = (PG==1) ? 0 : (t/GRP);
  const int rem = (PG==1) ? t : (t%GRP);
  const int a = rem / C;
  const int c = rem % C;

  float acc[9];
  #pragma unroll
  for (int m=0;m<9;++m) acc[m]=0.f;

  for (int k=0; k<32; ++k){
    // ---- h phase: threads (row); w1 chunked -> conflict-free b128 ----
    if (t < 180){
      float4 a0 = *reinterpret_cast<const float4*>(&sw1c[t*4]);
      float4 a1 = *reinterpret_cast<const float4*>(&sw1c[(180+t)*4]);
      float4 a2 = *reinterpret_cast<const float4*>(&sw1c[(360+t)*4]);
      float bb = sb1[t];
      for (int aa=0; aa<A; ++aa){
        const float* rb = &srbf[aa*12];
        float4 r0 = *reinterpret_cast<const float4*>(rb);
        float4 r1 = *reinterpret_cast<const float4*>(rb+4);
        float4 r2 = *reinterpret_cast<const float4*>(rb+8);
        float v = bb
          + a0.x*r0.x + a0.y*r0.y + a0.z*r0.z + a0.w*r0.w
          + a1.x*r1.x + a1.y*r1.y + a1.z*r1.z + a1.w*r1.w
          + a2.x*r2.x + a2.y*r2.y + a2.z*r2.z + a2.w*r2.w;
        sh[aa*180 + t] = fmaxf(v, 0.f);
      }
    }
    // ---- G phase ----
    gphase<A,0>(t, sY, sCG, sG);
    __syncthreads();
    // ---- stage next k (overlaps inner; srbf/sY not read by inner) ----
    if (k+1 < 32) stage(k+1);
    // ---- inner ----
    {
      i64 at = atom0 + a; if (at >= (i64)N) at = N-1;
      int nei = nei_idx[at*32 + k];
      const float* vr = Vp + ((i64)nei*C + c)*12;
      float vg[9];
      float4 v0 = *reinterpret_cast<const float4*>(vr);
      float4 v1 = *reinterpret_cast<const float4*>(vr+4);
      vg[0]=v0.x; vg[1]=v0.y; vg[2]=v0.z; vg[3]=v0.w;
      vg[4]=v1.x; vg[5]=v1.y; vg[6]=v1.z; vg[7]=v1.w;
      vg[8]=vr[8];
      if constexpr (PG==1){
        ipath<C,0,NPATH>(sw2c,sb2,c,&sh[a*180],&sG[a*GPTOT],vg,acc);
      } else if constexpr (PG==2){
        if (pg==0) ipath<C,0,10>(sw2c,sb2,c,&sh[a*180],&sG[a*GPTOT],vg,acc);
        else       ipath<C,10,NPATH>(sw2c,sb2,c,&sh[a*180],&sG[a*GPTOT],vg,acc);
      } else { // PG==3, splits balanced by per-path cost
        if      (pg==0) ipath<C,0,6>(sw2c,sb2,c,&sh[a*180],&sG[a*GPTOT],vg,acc);
        else if (pg==1) ipath<C,6,11>(sw2c,sb2,c,&sh[a*180],&sG[a*GPTOT],vg,acc);
        else            ipath<C,11,NPATH>(sw2c,sb2,c,&sh[a*180],&sG[a*GPTOT],vg,acc);
      }
    }
    __syncthreads();
  }

  // ---- store (PG>1: combine path-group partials via LDS) ----
  i64 at = atom0 + a;
  if constexpr (PG==1){
    if (at < (i64)N){
      float* orow = O + (at*C + c)*12;
      *reinterpret_cast<float4*>(orow)   = make_float4(acc[0],acc[1],acc[2],acc[3]);
      *reinterpret_cast<float4*>(orow+4) = make_float4(acc[4],acc[5],acc[6],acc[7]);
      orow[8] = acc[8];
    }
  } else {
    if (pg > 0){
      float* red = &sh[((pg-1)*GRP + rem)*9];
      #pragma unroll
      for (int m=0;m<9;++m) red[m]=acc[m];
    }
    __syncthreads();
    if (pg==0 && at < (i64)N){
      #pragma unroll
      for (int g=1; g<PG; ++g){
        const float* red = &sh[((g-1)*GRP + rem)*9];
        #pragma unroll
        for (int m=0;m<9;++m) acc[m] += red[m];
      }
      float* orow = O + (at*C + c)*12;
      *reinterpret_cast<float4*>(orow)   = make_float4(acc[0],acc[1],acc[2],acc[3]);
      *reinterpret_cast<float4*>(orow+4) = make_float4(acc[4],acc[5],acc[6],acc[7]);
      orow[8] = acc[8];
    }
  }
}

// ---------------- per-atom norm + siB + per-channel global sums ----------------
template<int C>
__global__ __launch_bounds__(64) void normsiB_kernel(
    const float* __restrict__ O, const float* __restrict__ w, const float* __restrict__ b,
    float* __restrict__ Vb, float* __restrict__ gsum, int N)
{
  __shared__ float sW[C*C];
  __shared__ float sO[C*9];
  __shared__ float sg[2*C];
  const int t = threadIdx.x;
  for (int e=t; e<C*C; e+=64) sW[e]=w[e];
  for (int e=t; e<2*C; e+=64) sg[e]=0.f;
  __syncthreads();
  const int iters = (N + gridDim.x - 1)/gridDim.x;
  for (int it=0; it<iters; ++it){
    i64 at = (i64)blockIdx.x + (i64)it*gridDim.x;
    float p0=0.f,p1=0.f,p2=0.f;
    if (at<(i64)N){
      for (int e=t; e<C*9; e+=64){
        int cc=e/9, m=e-cc*9;
        float v = O[((i64)at*C+cc)*12+m];
        sO[e]=v;
        float vv=v*v;
        if (m==0) p0+=vv; else if (m<4) p1+=vv; else p2+=vv;
      }
    }
    #pragma unroll
    for (int off=1; off<64; off<<=1){
      p0 += __shfl_xor(p0, off);
      p1 += __shfl_xor(p1, off);
      p2 += __shfl_xor(p2, off);
    }
    float i0 = 1.f/sqrtf(fmaxf(p0, EPSF));
    float i1 = 1.f/sqrtf(fmaxf(p1, EPSF));
    float i2 = 1.f/sqrtf(fmaxf(p2, EPSF));
    __syncthreads();
    if (at<(i64)N){
      for (int e=t; e<C*9; e+=64){
        int d=e/9, m=e-d*9;
        float inv = (m==0)? i0 : (m<4)? i1 : i2;
        const float* wr = &sW[d*C];
        float s=0.f;
        #pragma unroll
        for (int cc=0; cc<C; ++cc) s += wr[cc]*sO[cc*9+m];
        float outv = s*inv + ((m==0)? b[d] : 0.f);
        Vb[((i64)at*C+d)*12+m]=outv;
        if (m>=1) atomicAdd(&sg[(m<4?0:1)*C + d], outv*outv);
      }
    }
    __syncthreads();
  }
  for (int e=t; e<2*C; e+=64) atomicAdd(&gsum[e], sg[e]);
}

// ---------------- fused nonlinearity + next-layer siA ----------------
template<int Ci, int Co>
__global__ __launch_bounds__(64) void siaNL_kernel(
    const float* __restrict__ Vb, const float* __restrict__ gsum, const float* __restrict__ nlb,
    const float* __restrict__ w, const float* __restrict__ b, float* __restrict__ Vp, int N)
{
  __shared__ float sW[Co*Ci];
  __shared__ float sIn[Ci*9];
  __shared__ float sT[2*Ci];
  const int t=threadIdx.x;
  for (int e=t; e<Co*Ci; e+=64) sW[e]=w[e];
  for (int e=t; e<2*Ci;  e+=64) sT[e] = sqrtf(gsum[e]) + nlb[e];
  __syncthreads();
  const int iters = (N + gridDim.x - 1)/gridDim.x;
  for (int it=0; it<iters; ++it){
    i64 at = (i64)blockIdx.x + (i64)it*gridDim.x;
    if (at<(i64)N){
      for (int e=t; e<Ci*9; e+=64){
        int cc=e/9, m=e-cc*9;
        float v = Vb[((i64)at*Ci+cc)*12+m];
        float x = (m==0)? sspf(v) : (m<4)? v*sT[cc] : v*sT[Ci+cc];
        sIn[e]=x;
      }
    }
    __syncthreads();
    if (at<(i64)N){
      for (int e=t; e<Co*9; e+=64){
        int d=e/9, m=e-d*9;
        const float* wr=&sW[d*Ci];
        float s = (m==0)? b[d] : 0.f;
        #pragma unroll
        for (int cc=0;cc<Ci;++cc) s += wr[cc]*sIn[cc*9+m];
        Vp[((i64)at*Co+d)*12+m]=s;
      }
    }
    __syncthreads();
  }
}

// ---------------- final readout ----------------
__global__ void final_reduce_kernel(const float* __restrict__ Vb, float* __restrict__ Eacc, int N){
  __shared__ float sE[4];
  const int t=threadIdx.x;
  if (t<4) sE[t]=0.f;
  __syncthreads();
  float a0=0.f,a1=0.f,a2=0.f,a3=0.f;
  for (i64 at = (i64)blockIdx.x*blockDim.x + t; at < (i64)N; at += (i64)gridDim.x*blockDim.x){
    const float* row = Vb + at*4*12;
    a0 += sspf(row[0]);  a1 += sspf(row[12]);
    a2 += sspf(row[24]); a3 += sspf(row[36]);
  }
  atomicAdd(&sE[0],a0); atomicAdd(&sE[1],a1);
  atomicAdd(&sE[2],a2); atomicAdd(&sE[3],a3);
  __syncthreads();
  if (t<4) atomicAdd(&Eacc[t], sE[t]);
}

__global__ void final_dense_kernel(const float* __restrict__ Eacc,
    const float* __restrict__ w1,const float* __restrict__ b1,
    const float* __restrict__ w2,const float* __restrict__ b2,
    const float* __restrict__ w3,const float* __restrict__ b3,
    float* __restrict__ out)
{
  __shared__ float sE1[4];
  __shared__ float sH[256];
  const int t=threadIdx.x;
  if (t<4){
    float v=b1[t];
    #pragma unroll
    for (int j=0;j<4;j++) v += w1[t*4+j]*Eacc[j];
    sE1[t] = (v>0.f)? v : expm1f(v);
  }
  __syncthreads();
  {
    float v=b2[t];
    #pragma unroll
    for (int j=0;j<4;j++) v += w2[t*4+j]*sE1[j];
    sH[t]=v;
  }
  __syncthreads();
  if (t==0){
    float s=b3[0];
    for (int j=0;j<256;j++) s += w3[j]*sH[j];
    out[0]=s;
  }
}

// ---------------- launcher ----------------
extern "C" void kernel_launch(void* const* d_in, const int* in_sizes, int n_in,
                              void* d_out, int out_size, void* d_ws, size_t ws_size,
                              hipStream_t stream)
{
  const int* atom_types = (const int*)d_in[0];
  const int* nei_idx    = (const int*)d_in[1];
  const float* nei_vec  = (const float*)d_in[2];
  const float* in_f[36];
  for (int i=0;i<36 && i<n_in;i++) in_f[i] = (const float*)d_in[i];
  const int N = in_sizes[0];

  const i64 bsz = (i64)N*24*12;
  const size_t needed = 8192 + (size_t)3*bsz*4;
  if (ws_size < needed) return;

  char* ws = (char*)d_ws;
  float* cg   = (float*)ws;
  float* accs = (float*)(ws + 4096);
  float* gs1 = accs; float* gs2 = accs+48; float* gs3 = accs+72; float* Eacc = accs+80;
  float* bufA = (float*)(ws + 8192);
  float* bufB = bufA + bsz;
  float* bufC = bufB + bsz;

  #define LP(l, j) in_f[3 + 9*(l) + (j)]
  hipMemsetAsync(accs, 0, 512, stream);
  cg_init_kernel<<<15, 64, 0, stream>>>(cg);

  // ---- layer 1 (C=24, A=8, PG=1) ----
  siA1_kernel<<<(N*24+255)/256, 256, 0, stream>>>(atom_types, LP(0,0), LP(0,1), bufB, N);
  conv_kernel<24,8,1><<<(N+7)/8, 192, 0, stream>>>(bufB, nei_idx, nei_vec,
      LP(0,2),LP(0,3),LP(0,4),LP(0,5), cg, bufC, N);
  normsiB_kernel<24><<<2048,64,0,stream>>>(bufC, LP(0,6), LP(0,7), bufA, gs1, N);
  // ---- layer 2 (C=12, A=16, PG=1) ----
  siaNL_kernel<24,12><<<2048,64,0,stream>>>(bufA, gs1, LP(0,8), LP(1,0), LP(1,1), bufB, N);
  conv_kernel<12,16,1><<<(N+15)/16, 192, 0, stream>>>(bufB, nei_idx, nei_vec,
      LP(1,2),LP(1,3),LP(1,4),LP(1,5), cg, bufC, N);
  normsiB_kernel<12><<<2048,64,0,stream>>>(bufC, LP(1,6), LP(1,7), bufA, gs2, N);
  // ---- layer 3 (C=4, A=16, PG=3) ----
  siaNL_kernel<12,4><<<2048,64,0,stream>>>(bufA, gs2, LP(1,8), LP(2,0), LP(2,1), bufB, N);
  conv_kernel<4,16,3><<<(N+15)/16, 192, 0, stream>>>(bufB, nei_idx, nei_vec,
      LP(2,2),LP(2,3),LP(2,4),LP(2,5), cg, bufC, N);
  normsiB_kernel<4><<<2048,64,0,stream>>>(bufC, LP(2,6), LP(2,7), bufA, gs3, N);
  // ---- readout ----
  final_reduce_kernel<<<128,256,0,stream>>>(bufA, Eacc, N);
  final_dense_kernel<<<1,256,0,stream>>>(Eacc, in_f[30],in_f[31],in_f[32],in_f[33],in_f[34],in_f[35],
                                         (float*)d_out);
  #undef LP
}